// Round 1
// baseline (2222.140 us; speedup 1.0000x reference)
//
#include <hip/hip_runtime.h>
#include <math.h>

#define W_WIN 5
#define NSUB 2
#define MAX_SEG 64
#define MAX_T 256
#define NWGB 8          // workgroups per batch (ODE)

__device__ __forceinline__ float softplusf(float v) {
    // jax.nn.softplus == logaddexp(v, 0) == max(v,0) + log1p(exp(-|v|))
    return fmaxf(v, 0.0f) + log1pf(expf(-fabsf(v)));
}

// ---------------- wave-level numpy-faithful reductions ----------------
__device__ __forceinline__ float npsum128(float e0, float e1) {
    int lane = threadIdx.x & 63;
    int k = lane & 7;
    float r = __shfl(e0, k, 64);
    #pragma unroll
    for (int m = 1; m < 8; ++m) r += __shfl(e0, k + 8 * m, 64);
    #pragma unroll
    for (int m = 0; m < 8; ++m) r += __shfl(e1, k + 8 * m, 64);
    float r0 = __shfl(r, 0, 64), r1 = __shfl(r, 1, 64), r2 = __shfl(r, 2, 64), r3 = __shfl(r, 3, 64);
    float r4 = __shfl(r, 4, 64), r5 = __shfl(r, 5, 64), r6 = __shfl(r, 6, 64), r7 = __shfl(r, 7, 64);
    return ((r0 + r1) + (r2 + r3)) + ((r4 + r5) + (r6 + r7));
}

__device__ __forceinline__ float wmax128(float e0, float e1) {
    float m = fmaxf(e0, e1);
    #pragma unroll
    for (int s = 1; s < 64; s <<= 1) m = fmaxf(m, __shfl_xor(m, s, 64));
    return m;
}

// ---------------- kernel 1: encoder (also writes traj_t output block) ----------------
__global__ void encode_kernel(const float* __restrict__ emb, const int* __restrict__ hi,
                              const float* __restrict__ w1, const float* __restrict__ b1,
                              const float* __restrict__ w2, const float* __restrict__ b2,
                              float* __restrict__ enc, float* __restrict__ out,
                              int B, int L, int D) {
    __shared__ float x[128];
    __shared__ float h[128];
    int row = blockIdx.x;           // 0 .. B*L-1
    int j = threadIdx.x;            // 0 .. D-1
    int idx = hi[row];
    x[j] = emb[(size_t)idx * D + j];
    __syncthreads();
    float s = b1[j];
    #pragma unroll 8
    for (int i = 0; i < 128; ++i) s += x[i] * w1[i * 128 + j];
    h[j] = fmaxf(s, 0.0f);
    __syncthreads();
    float o = b2[j];
    #pragma unroll 8
    for (int i = 0; i < 128; ++i) o += h[i] * w2[i * 128 + j];
    enc[(size_t)row * D + j] = o;
    int b = row / L, l = row % L;
    size_t OS = 2 + 2 * (size_t)L * D;
    out[(size_t)b * OS + 2 + (size_t)L * D + (size_t)l * D + j] = o;
}

// ---------------- kernel 1b: all window JSDs in parallel (1 wave / position) ----------------
__global__ __launch_bounds__(64) void jsd_kernel(
        const float* __restrict__ enc_all, const int* __restrict__ hl,
        float* __restrict__ jsdv, int L, int D) {
    const int b = blockIdx.x >> 7;
    const int j = blockIdx.x & 127;
    const int n = hl[b];
    if (n < 2 * W_WIN || j > n - 2 * W_WIN) return;
    const int lane = threadIdx.x;
    const float* r = enc_all + ((size_t)b * L + j) * D;
    float ml0 = ((((r[lane]       + r[128 + lane]) + r[256 + lane]) + r[384 + lane]) + r[512 + lane]) / 5.0f;
    float ml1 = ((((r[64 + lane]  + r[192 + lane]) + r[320 + lane]) + r[448 + lane]) + r[576 + lane]) / 5.0f;
    float mr0 = ((((r[640 + lane] + r[768 + lane]) + r[896 + lane]) + r[1024 + lane]) + r[1152 + lane]) / 5.0f;
    float mr1 = ((((r[704 + lane] + r[832 + lane]) + r[960 + lane]) + r[1088 + lane]) + r[1216 + lane]) / 5.0f;
    float mxl = wmax128(ml0, ml1), mxr = wmax128(mr0, mr1);
    float a0 = expf(ml0 - mxl), a1 = expf(ml1 - mxl);
    float c0 = expf(mr0 - mxr), c1 = expf(mr1 - mxr);
    float sl = npsum128(a0, a1), sr = npsum128(c0, c1);
    float p0 = a0 / sl + 1e-8f, p1 = a1 / sl + 1e-8f;
    float q0 = c0 / sr + 1e-8f, q1 = c1 / sr + 1e-8f;
    float sp = npsum128(p0, p1), sq = npsum128(q0, q1);
    p0 /= sp; p1 /= sp; q0 /= sq; q1 /= sq;
    float mv0 = 0.5f * (p0 + q0), mv1 = 0.5f * (p1 + q1);
    float t10 = p0 * logf(p0 / mv0), t11 = p1 * logf(p1 / mv1);
    float t20 = q0 * logf(q0 / mv0), t21 = q1 * logf(q1 / mv1);
    float s1 = npsum128(t10, t11), s2 = npsum128(t20, t21);
    if (lane == 0) jsdv[b * L + j] = 0.5f * s1 + 0.5f * s2;
}

// ---------------- kernel 2: plan building from precomputed JSDs (1 wave / batch) ----------------
__global__ __launch_bounds__(64) void plan_kernel(
        const float* __restrict__ enc_all, const float* __restrict__ ht,
        const int* __restrict__ hl, const float* __restrict__ pt,
        const float* __restrict__ jsdv,
        float* __restrict__ envs, float* __restrict__ dt_sched,
        int* __restrict__ envid, int* __restrict__ stateidx,
        int* __restrict__ Tcnt, int B, int L, int D) {
    const int b = blockIdx.x;
    const int lane = threadIdx.x;   // 0..63
    const float* encg = enc_all + (size_t)b * L * D;
    const float* times = ht + (size_t)b * L;

    __shared__ float encs[128 * 128];
    __shared__ double cand[160];
    __shared__ double bounds[40];
    __shared__ int starts[40];
    __shared__ int seg_s[40], seg_e[40];
    __shared__ int m_sh;

    for (int v = lane; v < 128 * 128 / 4; v += 64)
        ((float4*)encs)[v] = ((const float4*)encg)[v];
    int n = hl[b];
    __syncthreads();

    int nb = 1, ns = 1;             // uniform across the wave
    if (lane == 0) { bounds[0] = (double)times[0]; starts[0] = 0; }
    __syncthreads();

    if (n >= 2 * W_WIN) {
        int j = 0;
        while (j <= n - 2 * W_WIN) {
            float jsd = jsdv[b * L + j];        // uniform broadcast load
            if (jsd > 0.5f) {
                if (nb < 39 && ns < 39) {
                    if (lane == 0) {
                        bounds[nb] = ((double)times[j + W_WIN - 1] + (double)times[j + W_WIN]) * 0.5;
                        starts[ns] = j + W_WIN;
                    }
                    nb++; ns++;
                }
                j += W_WIN;
            } else {
                j += 1;
            }
        }
    }
    __syncthreads();

    {
        double lastb = bounds[nb - 1];
        if ((double)times[n - 1] > lastb) {
            if (lane == 0) bounds[nb] = (double)times[n - 1];
            nb++;
        }
    }
    if (lane == 0) {
        for (int si = 0; si < ns; ++si) {
            seg_s[si] = starts[si];
            seg_e[si] = (si + 1 < ns) ? (starts[si + 1] - 1) : (n - 1);
        }
    }
    __syncthreads();

    int C = 0;
    for (int si = 0; si < ns; ++si) {
        int s = seg_s[si], e = seg_e[si];
        if (lane == 0) {
            double t0 = bounds[si];
            double t1 = (si + 1 < nb) ? bounds[si + 1] : bounds[nb - 1];
            int m = 0;
            cand[m++] = t0;
            for (int l = s; l <= e; ++l) {
                double tv = (double)times[l];
                if (tv < t0 || tv > t1) continue;
                if (tv != cand[m - 1]) cand[m++] = tv;
            }
            if (t1 > cand[m - 1]) cand[m++] = t1;
            for (int k = 1; k < m; ++k)
                if (cand[k] - cand[k - 1] < 1e-6) cand[k] = cand[k - 1] + 1e-6;
            m_sh = m;
        }
        __syncthreads();
        int m = m_sh;
        int K = m - 1;
        if (C + K > MAX_T) K = MAX_T - C;
        for (int k = lane; k < K; k += 64) {
            dt_sched[b * MAX_T + C + k] = (float)(cand[k + 1] - cand[k]);
            envid[b * MAX_T + C + k] = si;
        }
        for (int l = s + lane; l <= e; l += 64) {
            double tv = (double)times[l];
            int best = 0;
            double bd = fabs(cand[0] - tv);
            for (int k = 1; k < m; ++k) {
                double dk = fabs(cand[k] - tv);
                if (dk < bd) { bd = dk; best = k; }
            }
            stateidx[b * L + l] = C + best;
        }
        __syncthreads();
        C += K;
    }

    if (lane == 0) {
        double ptv = (double)pt[b];
        if (ptv > bounds[nb - 1] + 1e-6 && C < MAX_T) {
            double a0d = bounds[nb - 1], a1d = ptv;
            if (a1d - a0d < 1e-6) a1d = a0d + 1e-6;
            dt_sched[b * MAX_T + C] = (float)(a1d - a0d);
            envid[b * MAX_T + C] = ns - 1;
            C++;
        }
        Tcnt[b] = C;
    }
    for (int si = 0; si < ns; ++si) {
        int s = seg_s[si], e = seg_e[si];
        float s0 = 0.0f, s1 = 0.0f;
        for (int l = s; l <= e; ++l) {
            s0 += encs[l * 128 + lane];
            s1 += encs[l * 128 + lane + 64];
        }
        float inv = 1.0f / (float)(e - s + 1);
        envs[((size_t)b * MAX_SEG + si) * 128 + lane] = s0 * inv;
        envs[((size_t)b * MAX_SEG + si) * 128 + lane + 64] = s1 * inv;
    }
}

// ---------------- stamped-word dataflow helpers ----------------
// 8-byte atomic {value, phase}: the stamp travels WITH the data. Agent-scope
// atomics bypass L1. Slots are DOUBLE-BUFFERED by phase parity: with only one
// rendezvous per substep, overwrite distance must be 2 phases — WG A writes
// parity-P slots at phase p+2 only after consuming phase p+1 from ALL WGs,
// which requires every WG published p+1, which requires every WG consumed
// phase p (including A's parity-P words). So no consumer can still be polling
// a slot when it is overwritten.
typedef unsigned long long u64;
__device__ __forceinline__ void publish(u64* slot, float v, int phase) {
    u64 pk = ((u64)(unsigned)phase << 32) | (u64)__float_as_uint(v);
    __hip_atomic_store(slot, pk, __ATOMIC_RELAXED, __HIP_MEMORY_SCOPE_AGENT);
}

// ---------------- kernel 3: per-batch cooperative ODE, ONE edge/substep ----------------
// grid = 8*NWGB blocks x 512 thr. batch = blockIdx%8 (keeps all 8 WGs of a
// batch on one XCD under round-robin dispatch), g = blockIdx/8.
//
// Partition (vs previous 2-edge version): WG g owns h1 cols [g*64,g*64+64)
// (W1 col-slice in LDS, transposed). W2 is ROW-partitioned to match: WG g
// computes a full-width 512-elem partial pre_h2 from its own h1 slice
// (w2r: 64 regs/thread). That partial is the ONLY cross-WG exchange. After
// summing the 8 partials (tree order), every WG has the full h2 and applies
// softplus redundantly. Each WG holds ALL of W3 (w3p: 128 regs/thread) and
// computes the full dz locally — the old z-partial edge is gone, and z never
// leaves the WG again.
__global__ __launch_bounds__(512, 1) void ode_coop(
    const float* __restrict__ usert, const int* __restrict__ u,
    const float* __restrict__ vw1, const float* __restrict__ vb1,
    const float* __restrict__ vw2, const float* __restrict__ vb2,
    const float* __restrict__ vw3, const float* __restrict__ vb3,
    const float* __restrict__ emb, const int* __restrict__ pos, const int* __restrict__ neg,
    const float* __restrict__ envs, const float* __restrict__ dtsch,
    const int* __restrict__ envid, const int* __restrict__ stidx,
    const int* __restrict__ Tc,
    u64* pst,
    float* out, int B)
{
    const int batch = blockIdx.x & 7;
    if (batch >= B) return;
    const int g = blockIdx.x >> 3;      // 0..7
    const int tid = threadIdx.x;        // 0..511

    // layer-1 mapping: cl = h1 col-in-slice (0..63), q = input-eighth (0..7)
    const int cl = tid >> 3, q = tid & 7;
    // layer-3 mapping: cz = z col (0..127), r = h2-row-quarter (0..3)
    const int cz = tid >> 2, r = tid & 3;

    // W1 col-slice, transposed [64][256], row stride padded to 260 so the
    // 8 q-chunks of one cl land on distinct 4-bank windows (260%32==4).
    __shared__ float w1t[64 * 260];
    __shared__ float xs[256];           // [z | env]
    __shared__ float h1loc[64];         // this WG's h1 slice
    __shared__ float h2s[512];          // FULL h2 (redundant per WG)
    __shared__ int sidx_sh[128];
    __shared__ float dts_sh[MAX_T];
    __shared__ int sid_sh[MAX_T];

    // ---- one-time weight staging ----
    {   // coalesced: each wave reads 64 consecutive cols of row i, scatters transposed
        const int lane = tid & 63;
        for (int i = tid >> 6; i < 256; i += 8)
            w1t[lane * 260 + i] = vw1[(size_t)i * 512 + g * 64 + lane];
    }
    float w2r[64];                      // W2[g*64+i][tid], i=0..63 (row-slice, own output col)
    #pragma unroll
    for (int i = 0; i < 64; ++i)
        w2r[i] = vw2[(size_t)(g * 64 + i) * 512 + tid];
    float w3p[128];                     // W3[r*128+k][cz], k=0..127 (full W3 across the WG)
    #pragma unroll
    for (int k = 0; k < 128; ++k)
        w3p[k] = vw3[(size_t)(r * 128 + k) * 128 + cz];

    const float b1c = vb1[g * 64 + cl];
    const float b2c = vb2[tid];
    const float b3c = vb3[cz];

    if (tid < 128) sidx_sh[tid] = stidx[batch * 128 + tid];
    if (tid < MAX_T) {
        dts_sh[tid] = dtsch[batch * MAX_T + tid];
        sid_sh[tid] = envid[batch * MAX_T + tid];
    }

    const int T = Tc[batch];
    u64* pbase = pst + (size_t)batch * 8192;        // 2 parities x 8 WGs x 512 words
    const size_t OS = 2 + 2 * (size_t)128 * 128;
    float* outb = out + (size_t)batch * OS;

    // init z into LDS (every WG loads it directly — no exchange)
    if (tid < 128) xs[tid] = usert[(size_t)u[batch] * 128 + tid];
    __syncthreads();

    // m=0 records (g==0 writes full rows)
    int lp = 0;
    if (g == 0) {
        while (lp < 128 && sidx_sh[lp] == 0) {
            if (tid < 128) outb[2 + (size_t)lp * 128 + tid] = xs[tid];
            ++lp;
        }
    }

    int phase = 0;
    for (int t = 0; t < T; ++t) {
        const int si = sid_sh[t];
        const float hdt = dts_sh[t] * 0.5f;                 // dt / NSUB
        const float* envp = envs + ((size_t)batch * MAX_SEG + si) * 128;
        if (tid >= 128 && tid < 256) xs[tid] = envp[tid - 128];
        __syncthreads();
        #pragma unroll
        for (int sub = 0; sub < NSUB; ++sub) {
            ++phase;
            // ---- layer 1: 256 -> 64 slice (W1 from LDS), reduce 8 q-lanes ----
            float a0 = 0.0f, a1 = 0.0f;
            #pragma unroll
            for (int i4 = 0; i4 < 8; ++i4) {
                float4 wv = *(const float4*)(w1t + cl * 260 + q * 32 + i4 * 4);
                float4 xv = *(const float4*)(xs + q * 32 + i4 * 4);
                float d = wv.x * xv.x + wv.y * xv.y + wv.z * xv.z + wv.w * xv.w;
                if (i4 & 1) a1 += d; else a0 += d;
            }
            float acc = a0 + a1;
            #pragma unroll
            for (int s = 1; s < 8; s <<= 1) acc += __shfl_xor(acc, s, 64);
            if (q == 0) h1loc[cl] = softplusf(acc + b1c);
            __syncthreads();
            // ---- layer 2 ROW-partial: own 64 h1 rows -> full-width pre_h2[tid] ----
            float p0 = 0.0f, p1 = 0.0f, p2 = 0.0f, p3 = 0.0f;
            #pragma unroll
            for (int i4 = 0; i4 < 16; ++i4) {
                float4 hv = *(const float4*)(h1loc + i4 * 4);     // broadcast, conflict-free
                float d = w2r[i4 * 4 + 0] * hv.x + w2r[i4 * 4 + 1] * hv.y
                        + w2r[i4 * 4 + 2] * hv.z + w2r[i4 * 4 + 3] * hv.w;
                switch (i4 & 3) { case 0: p0 += d; break; case 1: p1 += d; break;
                                  case 2: p2 += d; break; default: p3 += d; }
            }
            float pown = (p0 + p1) + (p2 + p3);
            // ---- the ONE edge: publish own partial, poll the 7 remote ones ----
            u64* pbuf = pbase + (size_t)(phase & 1) * 4096;       // parity double-buffer
            publish(&pbuf[(size_t)g * 512 + tid], pown, phase);
            u64 got[8];
            bool ok;
            do {
                ok = true;
                #pragma unroll
                for (int g2 = 0; g2 < 8; ++g2)
                    if (g2 != g)
                        got[g2] = __hip_atomic_load(&pbuf[(size_t)g2 * 512 + tid],
                                                    __ATOMIC_RELAXED, __HIP_MEMORY_SCOPE_AGENT);
                #pragma unroll
                for (int g2 = 0; g2 < 8; ++g2)
                    if (g2 != g) ok &= ((int)(got[g2] >> 32) == phase);
                if (!ok) __builtin_amdgcn_s_sleep(1);
            } while (!ok);
            float pv[8];
            #pragma unroll
            for (int g2 = 0; g2 < 8; ++g2)
                pv[g2] = (g2 == g) ? pown : __uint_as_float((unsigned)got[g2]);
            // tree-8 combine (same association shape as the old shfl butterfly)
            float pre = ((pv[0] + pv[1]) + (pv[2] + pv[3])) + ((pv[4] + pv[5]) + (pv[6] + pv[7]));
            h2s[tid] = softplusf(pre + b2c);
            __syncthreads();
            // ---- layer 3 FULL: 512 h2 rows -> dz[cz], 4 lanes x 128 rows each ----
            float c0 = 0.0f, c1 = 0.0f, c2 = 0.0f, c3 = 0.0f;
            #pragma unroll
            for (int k4 = 0; k4 < 32; ++k4) {
                float4 hv = *(const float4*)(h2s + r * 128 + k4 * 4);
                float d = w3p[k4 * 4 + 0] * hv.x + w3p[k4 * 4 + 1] * hv.y
                        + w3p[k4 * 4 + 2] * hv.z + w3p[k4 * 4 + 3] * hv.w;
                switch (k4 & 3) { case 0: c0 += d; break; case 1: c1 += d; break;
                                  case 2: c2 += d; break; default: c3 += d; }
            }
            float az = (c0 + c1) + (c2 + c3);
            az += __shfl_xor(az, 1, 64);
            az += __shfl_xor(az, 2, 64);
            if (r == 0) xs[cz] = xs[cz] + hdt * (az + b3c);
            __syncthreads();
        }
        // record states at grid index m = t+1 (g==0 writes full rows from xs)
        if (g == 0) {
            const int m = t + 1;
            while (lp < 128 && sidx_sh[lp] == m) {
                if (tid < 128) outb[2 + (size_t)lp * 128 + tid] = xs[tid];
                ++lp;
            }
        }
    }
    // epilogue: scores (g==0; final z in xs)
    if (g == 0 && tid < 128) {
        int lane = tid & 63;
        const int item = (tid < 64) ? pos[batch] : neg[batch];
        const float* ev = emb + (size_t)item * 128;
        float sacc = xs[lane] * ev[lane] + xs[lane + 64] * ev[lane + 64];
        #pragma unroll
        for (int s = 1; s < 64; s <<= 1) sacc += __shfl_xor(sacc, s, 64);
        if (lane == 0) outb[(tid < 64) ? 0 : 1] = sacc;
    }
}

extern "C" void kernel_launch(void* const* d_in, const int* in_sizes, int n_in,
                              void* d_out, int out_size, void* d_ws, size_t ws_size,
                              hipStream_t stream) {
    const float* emb   = (const float*)d_in[0];
    const float* w1    = (const float*)d_in[1];
    const float* b1    = (const float*)d_in[2];
    const float* w2    = (const float*)d_in[3];
    const float* b2    = (const float*)d_in[4];
    const float* usert = (const float*)d_in[5];
    const float* vw1   = (const float*)d_in[6];
    const float* vb1   = (const float*)d_in[7];
    const float* vw2   = (const float*)d_in[8];
    const float* vb2   = (const float*)d_in[9];
    const float* vw3   = (const float*)d_in[10];
    const float* vb3   = (const float*)d_in[11];
    const int*   u     = (const int*)d_in[12];
    const int*   hi    = (const int*)d_in[13];
    const float* ht    = (const float*)d_in[14];
    const int*   hl    = (const int*)d_in[15];
    const int*   pos   = (const int*)d_in[16];
    const int*   neg   = (const int*)d_in[17];
    const float* pt    = (const float*)d_in[18];

    int D = in_sizes[2];         // 128
    int B = in_sizes[12];        // 4
    int L = in_sizes[13] / B;    // 128

    // workspace carve-up: stamped exchange buffer first (8B aligned)
    // pst: 8 batch slots x 2 parities x 8 WGs x 512 words
    u64*   pst      = (u64*)d_ws;
    float* jsdv     = (float*)(pst + 8 * 8192);             // B*L
    float* enc      = jsdv + (size_t)B * L;                 // B*L*D
    float* envsb    = enc + (size_t)B * L * D;              // B*MAX_SEG*D
    float* dt_sched = envsb + (size_t)B * MAX_SEG * D;      // B*MAX_T
    int*   envid    = (int*)(dt_sched + (size_t)B * MAX_T); // B*MAX_T
    int*   stateidx = envid + (size_t)B * MAX_T;            // B*L
    int*   Tcnt     = stateidx + (size_t)B * L;             // B

    hipMemsetAsync(pst, 0, 8 * 8192 * sizeof(u64), stream); // stamps=0 < phase 1
    encode_kernel<<<B * L, D, 0, stream>>>(emb, hi, w1, b1, w2, b2, enc, (float*)d_out, B, L, D);
    jsd_kernel<<<B * 128, 64, 0, stream>>>(enc, hl, jsdv, L, D);
    plan_kernel<<<B, 64, 0, stream>>>(enc, ht, hl, pt, jsdv, envsb, dt_sched, envid, stateidx, Tcnt, B, L, D);
    ode_coop<<<8 * NWGB, 512, 0, stream>>>(usert, u, vw1, vb1, vw2, vb2, vw3, vb3, emb, pos, neg,
                                           envsb, dt_sched, envid, stateidx, Tcnt,
                                           pst, (float*)d_out, B);
}

// Round 2
// 1348.149 us; speedup vs baseline: 1.6483x; 1.6483x over previous
//
#include <hip/hip_runtime.h>
#include <math.h>

#define W_WIN 5
#define NSUB 2
#define MAX_SEG 64
#define MAX_T 256
#define NWGB 8          // workgroups per batch (ODE)
#define FAST_ITERS 24   // L2 fast-path poll budget before permanent fallback

__device__ __forceinline__ float softplusf(float v) {
    // jax.nn.softplus == logaddexp(v, 0) == max(v,0) + log1p(exp(-|v|))
    return fmaxf(v, 0.0f) + log1pf(expf(-fabsf(v)));
}

// ---------------- wave-level numpy-faithful reductions ----------------
__device__ __forceinline__ float npsum128(float e0, float e1) {
    int lane = threadIdx.x & 63;
    int k = lane & 7;
    float r = __shfl(e0, k, 64);
    #pragma unroll
    for (int m = 1; m < 8; ++m) r += __shfl(e0, k + 8 * m, 64);
    #pragma unroll
    for (int m = 0; m < 8; ++m) r += __shfl(e1, k + 8 * m, 64);
    float r0 = __shfl(r, 0, 64), r1 = __shfl(r, 1, 64), r2 = __shfl(r, 2, 64), r3 = __shfl(r, 3, 64);
    float r4 = __shfl(r, 4, 64), r5 = __shfl(r, 5, 64), r6 = __shfl(r, 6, 64), r7 = __shfl(r, 7, 64);
    return ((r0 + r1) + (r2 + r3)) + ((r4 + r5) + (r6 + r7));
}

__device__ __forceinline__ float wmax128(float e0, float e1) {
    float m = fmaxf(e0, e1);
    #pragma unroll
    for (int s = 1; s < 64; s <<= 1) m = fmaxf(m, __shfl_xor(m, s, 64));
    return m;
}

// ---------------- kernel 1: encoder (also writes traj_t output block) ----------------
__global__ void encode_kernel(const float* __restrict__ emb, const int* __restrict__ hi,
                              const float* __restrict__ w1, const float* __restrict__ b1,
                              const float* __restrict__ w2, const float* __restrict__ b2,
                              float* __restrict__ enc, float* __restrict__ out,
                              int B, int L, int D) {
    __shared__ float x[128];
    __shared__ float h[128];
    int row = blockIdx.x;           // 0 .. B*L-1
    int j = threadIdx.x;            // 0 .. D-1
    int idx = hi[row];
    x[j] = emb[(size_t)idx * D + j];
    __syncthreads();
    float s = b1[j];
    #pragma unroll 8
    for (int i = 0; i < 128; ++i) s += x[i] * w1[i * 128 + j];
    h[j] = fmaxf(s, 0.0f);
    __syncthreads();
    float o = b2[j];
    #pragma unroll 8
    for (int i = 0; i < 128; ++i) o += h[i] * w2[i * 128 + j];
    enc[(size_t)row * D + j] = o;
    int b = row / L, l = row % L;
    size_t OS = 2 + 2 * (size_t)L * D;
    out[(size_t)b * OS + 2 + (size_t)L * D + (size_t)l * D + j] = o;
}

// ---------------- kernel 1b: all window JSDs in parallel (1 wave / position) ----------------
__global__ __launch_bounds__(64) void jsd_kernel(
        const float* __restrict__ enc_all, const int* __restrict__ hl,
        float* __restrict__ jsdv, int L, int D) {
    const int b = blockIdx.x >> 7;
    const int j = blockIdx.x & 127;
    const int n = hl[b];
    if (n < 2 * W_WIN || j > n - 2 * W_WIN) return;
    const int lane = threadIdx.x;
    const float* r = enc_all + ((size_t)b * L + j) * D;
    float ml0 = ((((r[lane]       + r[128 + lane]) + r[256 + lane]) + r[384 + lane]) + r[512 + lane]) / 5.0f;
    float ml1 = ((((r[64 + lane]  + r[192 + lane]) + r[320 + lane]) + r[448 + lane]) + r[576 + lane]) / 5.0f;
    float mr0 = ((((r[640 + lane] + r[768 + lane]) + r[896 + lane]) + r[1024 + lane]) + r[1152 + lane]) / 5.0f;
    float mr1 = ((((r[704 + lane] + r[832 + lane]) + r[960 + lane]) + r[1088 + lane]) + r[1216 + lane]) / 5.0f;
    float mxl = wmax128(ml0, ml1), mxr = wmax128(mr0, mr1);
    float a0 = expf(ml0 - mxl), a1 = expf(ml1 - mxl);
    float c0 = expf(mr0 - mxr), c1 = expf(mr1 - mxr);
    float sl = npsum128(a0, a1), sr = npsum128(c0, c1);
    float p0 = a0 / sl + 1e-8f, p1 = a1 / sl + 1e-8f;
    float q0 = c0 / sr + 1e-8f, q1 = c1 / sr + 1e-8f;
    float sp = npsum128(p0, p1), sq = npsum128(q0, q1);
    p0 /= sp; p1 /= sp; q0 /= sq; q1 /= sq;
    float mv0 = 0.5f * (p0 + q0), mv1 = 0.5f * (p1 + q1);
    float t10 = p0 * logf(p0 / mv0), t11 = p1 * logf(p1 / mv1);
    float t20 = q0 * logf(q0 / mv0), t21 = q1 * logf(q1 / mv1);
    float s1 = npsum128(t10, t11), s2 = npsum128(t20, t21);
    if (lane == 0) jsdv[b * L + j] = 0.5f * s1 + 0.5f * s2;
}

// ---------------- kernel 2: plan building from precomputed JSDs (1 wave / batch) ----------------
__global__ __launch_bounds__(64) void plan_kernel(
        const float* __restrict__ enc_all, const float* __restrict__ ht,
        const int* __restrict__ hl, const float* __restrict__ pt,
        const float* __restrict__ jsdv,
        float* __restrict__ envs, float* __restrict__ dt_sched,
        int* __restrict__ envid, int* __restrict__ stateidx,
        int* __restrict__ Tcnt, int B, int L, int D) {
    const int b = blockIdx.x;
    const int lane = threadIdx.x;   // 0..63
    const float* encg = enc_all + (size_t)b * L * D;
    const float* times = ht + (size_t)b * L;

    __shared__ float encs[128 * 128];
    __shared__ double cand[160];
    __shared__ double bounds[40];
    __shared__ int starts[40];
    __shared__ int seg_s[40], seg_e[40];
    __shared__ int m_sh;

    for (int v = lane; v < 128 * 128 / 4; v += 64)
        ((float4*)encs)[v] = ((const float4*)encg)[v];
    int n = hl[b];
    __syncthreads();

    int nb = 1, ns = 1;             // uniform across the wave
    if (lane == 0) { bounds[0] = (double)times[0]; starts[0] = 0; }
    __syncthreads();

    if (n >= 2 * W_WIN) {
        int j = 0;
        while (j <= n - 2 * W_WIN) {
            float jsd = jsdv[b * L + j];        // uniform broadcast load
            if (jsd > 0.5f) {
                if (nb < 39 && ns < 39) {
                    if (lane == 0) {
                        bounds[nb] = ((double)times[j + W_WIN - 1] + (double)times[j + W_WIN]) * 0.5;
                        starts[ns] = j + W_WIN;
                    }
                    nb++; ns++;
                }
                j += W_WIN;
            } else {
                j += 1;
            }
        }
    }
    __syncthreads();

    {
        double lastb = bounds[nb - 1];
        if ((double)times[n - 1] > lastb) {
            if (lane == 0) bounds[nb] = (double)times[n - 1];
            nb++;
        }
    }
    if (lane == 0) {
        for (int si = 0; si < ns; ++si) {
            seg_s[si] = starts[si];
            seg_e[si] = (si + 1 < ns) ? (starts[si + 1] - 1) : (n - 1);
        }
    }
    __syncthreads();

    int C = 0;
    for (int si = 0; si < ns; ++si) {
        int s = seg_s[si], e = seg_e[si];
        if (lane == 0) {
            double t0 = bounds[si];
            double t1 = (si + 1 < nb) ? bounds[si + 1] : bounds[nb - 1];
            int m = 0;
            cand[m++] = t0;
            for (int l = s; l <= e; ++l) {
                double tv = (double)times[l];
                if (tv < t0 || tv > t1) continue;
                if (tv != cand[m - 1]) cand[m++] = tv;
            }
            if (t1 > cand[m - 1]) cand[m++] = t1;
            for (int k = 1; k < m; ++k)
                if (cand[k] - cand[k - 1] < 1e-6) cand[k] = cand[k - 1] + 1e-6;
            m_sh = m;
        }
        __syncthreads();
        int m = m_sh;
        int K = m - 1;
        if (C + K > MAX_T) K = MAX_T - C;
        for (int k = lane; k < K; k += 64) {
            dt_sched[b * MAX_T + C + k] = (float)(cand[k + 1] - cand[k]);
            envid[b * MAX_T + C + k] = si;
        }
        for (int l = s + lane; l <= e; l += 64) {
            double tv = (double)times[l];
            int best = 0;
            double bd = fabs(cand[0] - tv);
            for (int k = 1; k < m; ++k) {
                double dk = fabs(cand[k] - tv);
                if (dk < bd) { bd = dk; best = k; }
            }
            stateidx[b * L + l] = C + best;
        }
        __syncthreads();
        C += K;
    }

    if (lane == 0) {
        double ptv = (double)pt[b];
        if (ptv > bounds[nb - 1] + 1e-6 && C < MAX_T) {
            double a0d = bounds[nb - 1], a1d = ptv;
            if (a1d - a0d < 1e-6) a1d = a0d + 1e-6;
            dt_sched[b * MAX_T + C] = (float)(a1d - a0d);
            envid[b * MAX_T + C] = ns - 1;
            C++;
        }
        Tcnt[b] = C;
    }
    for (int si = 0; si < ns; ++si) {
        int s = seg_s[si], e = seg_e[si];
        float s0 = 0.0f, s1 = 0.0f;
        for (int l = s; l <= e; ++l) {
            s0 += encs[l * 128 + lane];
            s1 += encs[l * 128 + lane + 64];
        }
        float inv = 1.0f / (float)(e - s + 1);
        envs[((size_t)b * MAX_SEG + si) * 128 + lane] = s0 * inv;
        envs[((size_t)b * MAX_SEG + si) * 128 + lane + 64] = s1 * inv;
    }
}

// ---------------- stamped-word dataflow helpers ----------------
// 8-byte {value, phase}: the stamp travels WITH the data, so a single load both
// detects readiness and delivers the value. TWO copies are published:
//  * FAST slot: plain (workgroup-scope) store. CDNA vector L1 is write-through,
//    so the store lands in the writer's XCD L2. Consumers poll it with an
//    inline-asm `global_load_dwordx2 ... sc0` (bypass L1 only, served by L2).
//    This works iff producer and consumer share an XCD — which the dispatch
//    heuristic (batch = blockIdx&7, round-robin blockIdx->XCD) arranges.
//  * SLOW slot: agent-scope atomic store (sc1, memory-side coherence point,
//    guaranteed visible across XCDs). Consumers fall back to it permanently
//    after FAST_ITERS failed fast polls, so a placement change degrades to
//    the old (proven) behavior instead of deadlocking.
// Overwrite distance (next write of a slot) transitively exceeds consume
// distance via the dataflow chain h1(p+1) <- z(p) <- zp(p) <- h2(p) <- h1(p),
// identically for both copies.
typedef unsigned long long u64;

__device__ __forceinline__ u64 packw(float v, int phase) {
    return ((u64)(unsigned)phase << 32) | (u64)__float_as_uint(v);
}
__device__ __forceinline__ void publish2(u64* fast, u64* slow, float v, int phase) {
    u64 pk = packw(v, phase);
    __hip_atomic_store(fast, pk, __ATOMIC_RELAXED, __HIP_MEMORY_SCOPE_WORKGROUP); // plain store -> L2
    __hip_atomic_store(slow, pk, __ATOMIC_RELAXED, __HIP_MEMORY_SCOPE_AGENT);     // sc1 -> memory-side
}
__device__ __forceinline__ u64 ld_sc0(const u64* p) {
    u64 v;
    asm volatile("global_load_dwordx2 %0, %1, off sc0\n\t"
                 "s_waitcnt vmcnt(0)"
                 : "=&v"(v) : "v"(p) : "memory");
    return v;
}

// ---------------- kernel 3: per-batch cooperative ODE, 2 edges/substep ----------------
// grid = 8*NWGB blocks x 512 thr. batch = blockIdx%8, g = blockIdx/8.
// WG g owns h1/h2 cols [g*64,g*64+64). Layer 3 uses LINEARITY: each WG computes a
// full-width z-partial from its OWN h2 slice (h2 never leaves the WG; stays in LDS);
// consumers sum the 8 partials in fixed order g=0..7. Per substep:
//   edge A: h1 slice exchange (512 stamped words)
//   edge B: z-partial exchange (8 x 128 stamped words)
// No barrier between publish and consume: each wave publishes its own words before
// polling others (program order) -> no circular wait; stamped words self-announce.
__global__ __launch_bounds__(512, 1) void ode_coop(
    const float* __restrict__ usert, const int* __restrict__ u,
    const float* __restrict__ vw1, const float* __restrict__ vb1,
    const float* __restrict__ vw2, const float* __restrict__ vb2,
    const float* __restrict__ vw3, const float* __restrict__ vb3,
    const float* __restrict__ emb, const int* __restrict__ pos, const int* __restrict__ neg,
    const float* __restrict__ envs, const float* __restrict__ dtsch,
    const int* __restrict__ envid, const int* __restrict__ stidx,
    const int* __restrict__ Tc,
    u64* h1f, u64* zpf, u64* h1st, u64* zpst,
    float* out, int B)
{
    const int batch = blockIdx.x & 7;
    if (batch >= B) return;
    const int g = blockIdx.x >> 3;      // 0..7
    const int tid = threadIdx.x;        // 0..511

    // L1/L2 mapping: cl = col-in-slice (0..63), q = input-eighth (0..7)
    const int cl = tid >> 3, q = tid & 7;
    const int c12 = g * 64 + cl;
    // L3-partial mapping: cz = z col (0..127), r = slice-row-quarter (0..3)
    const int cz = tid >> 2, r = tid & 3;

    __shared__ float xs[256];           // [z | env]
    __shared__ float h1s[512];
    __shared__ float h2s[64];           // THIS WG's h2 slice only
    __shared__ int sidx_sh[128];
    __shared__ float dts_sh[MAX_T];
    __shared__ int sid_sh[MAX_T];

    // ---- preload weight slices into registers, skewed order (static indices) ----
    float w1r[32], w2r[64], w3p[16];
    #pragma unroll
    for (int k4 = 0; k4 < 8; ++k4) {
        int jj = ((k4 + q) & 7) * 4;
        #pragma unroll
        for (int m = 0; m < 4; ++m)
            w1r[k4 * 4 + m] = vw1[(size_t)(q * 32 + jj + m) * 512 + c12];
    }
    #pragma unroll
    for (int k4 = 0; k4 < 16; ++k4) {
        int jj = ((k4 + 2 * q) & 15) * 4;
        #pragma unroll
        for (int m = 0; m < 4; ++m)
            w2r[k4 * 4 + m] = vw2[(size_t)(q * 64 + jj + m) * 512 + c12];
    }
    #pragma unroll
    for (int k = 0; k < 16; ++k)
        w3p[k] = vw3[(size_t)(g * 64 + r * 16 + k) * 128 + cz];
    const float bias1 = vb1[c12];
    const float bias2 = vb2[c12];
    const float b3c = (tid < 128) ? vb3[tid] : 0.0f;

    if (tid < 128) sidx_sh[tid] = stidx[batch * 128 + tid];
    if (tid < MAX_T) {
        dts_sh[tid] = dtsch[batch * MAX_T + tid];
        sid_sh[tid] = envid[batch * MAX_T + tid];
    }

    const int T = Tc[batch];
    u64* h1fb = h1f + batch * 512;
    u64* zpfb = zpf + batch * 1024;
    u64* h1b  = h1st + batch * 512;
    u64* zpb  = zpst + batch * 1024;
    const size_t OS = 2 + 2 * (size_t)128 * 128;
    float* outb = out + (size_t)batch * OS;

    bool use_fast = true;               // per-thread; cleared on first fast-path miss

    // init z into LDS (every WG loads it directly — no exchange)
    if (tid < 128) xs[tid] = usert[(size_t)u[batch] * 128 + tid];
    __syncthreads();

    // m=0 records (g==0 writes full rows)
    int lp = 0;
    if (g == 0) {
        while (lp < 128 && sidx_sh[lp] == 0) {
            if (tid < 128) outb[2 + (size_t)lp * 128 + tid] = xs[tid];
            ++lp;
        }
    }

    int phase = 0;
    for (int t = 0; t < T; ++t) {
        const int si = sid_sh[t];
        const float hdt = dts_sh[t] * 0.5f;                     // dt / NSUB
        const float* envp = envs + ((size_t)batch * MAX_SEG + si) * 128;
        if (tid >= 128 && tid < 256) xs[tid] = envp[tid - 128];
        __syncthreads();
        #pragma unroll
        for (int sub = 0; sub < NSUB; ++sub) {
            ++phase;
            // ---- layer 1: 256 -> 512 slice, partials over q, reduce 8 lanes ----
            float acc = 0.0f;
            #pragma unroll
            for (int k4 = 0; k4 < 8; ++k4) {
                int off = q * 32 + ((k4 + q) & 7) * 4;
                float4 xv = *(const float4*)(xs + off);
                acc += w1r[k4 * 4 + 0] * xv.x + w1r[k4 * 4 + 1] * xv.y
                     + w1r[k4 * 4 + 2] * xv.z + w1r[k4 * 4 + 3] * xv.w;
            }
            #pragma unroll
            for (int s = 1; s < 8; s <<= 1) acc += __shfl_xor(acc, s, 64);
            // edge A: publish h1 slice (fast+slow), consume full h1
            if (q == 0) publish2(&h1fb[c12], &h1b[c12], softplusf(acc + bias1), phase);
            {
                float h1v = 0.0f;
                bool have = false;
                if (use_fast) {
                    #pragma unroll 1
                    for (int it = 0; it < FAST_ITERS; ++it) {
                        u64 pk = ld_sc0(&h1fb[tid]);
                        if ((int)(pk >> 32) == phase) {
                            h1v = __uint_as_float((unsigned)pk); have = true; break;
                        }
                    }
                    if (!have) use_fast = false;
                }
                if (!have) {
                    for (;;) {
                        u64 pk = __hip_atomic_load(&h1b[tid], __ATOMIC_RELAXED, __HIP_MEMORY_SCOPE_AGENT);
                        if ((int)(pk >> 32) == phase) { h1v = __uint_as_float((unsigned)pk); break; }
                        __builtin_amdgcn_s_sleep(1);
                    }
                }
                h1s[tid] = h1v;
            }
            __syncthreads();
            // ---- layer 2: 512 -> 64 slice (stays in LDS, no exchange) ----
            float acc2 = 0.0f;
            #pragma unroll
            for (int k4 = 0; k4 < 16; ++k4) {
                int off = q * 64 + ((k4 + 2 * q) & 15) * 4;
                float4 xv = *(const float4*)(h1s + off);
                acc2 += w2r[k4 * 4 + 0] * xv.x + w2r[k4 * 4 + 1] * xv.y
                      + w2r[k4 * 4 + 2] * xv.z + w2r[k4 * 4 + 3] * xv.w;
            }
            #pragma unroll
            for (int s = 1; s < 8; s <<= 1) acc2 += __shfl_xor(acc2, s, 64);
            if (q == 0) h2s[cl] = softplusf(acc2 + bias2);
            __syncthreads();
            // ---- layer 3 PARTIAL: this WG's 64 h2 rows -> full 128-wide partial ----
            float az = 0.0f;
            #pragma unroll
            for (int k4 = 0; k4 < 4; ++k4) {
                float4 hv = *(const float4*)(h2s + r * 16 + k4 * 4);
                az += w3p[k4 * 4 + 0] * hv.x + w3p[k4 * 4 + 1] * hv.y
                    + w3p[k4 * 4 + 2] * hv.z + w3p[k4 * 4 + 3] * hv.w;
            }
            az += __shfl_xor(az, 1, 64);
            az += __shfl_xor(az, 2, 64);
            // edge B: publish z-partial (fast+slow), consume all 8 partials
            if (r == 0) publish2(&zpfb[g * 128 + cz], &zpb[g * 128 + cz], az, phase);
            if (tid < 128) {
                float sum = 0.0f;
                bool have = false;
                if (use_fast) {
                    const u64* a0 = &zpfb[0 * 128 + tid];
                    const u64* a1 = &zpfb[1 * 128 + tid];
                    const u64* a2 = &zpfb[2 * 128 + tid];
                    const u64* a3 = &zpfb[3 * 128 + tid];
                    const u64* a4 = &zpfb[4 * 128 + tid];
                    const u64* a5 = &zpfb[5 * 128 + tid];
                    const u64* a6 = &zpfb[6 * 128 + tid];
                    const u64* a7 = &zpfb[7 * 128 + tid];
                    #pragma unroll 1
                    for (int it = 0; it < FAST_ITERS && !have; ++it) {
                        u64 p0, p1, p2, p3, p4, p5, p6, p7;
                        asm volatile(
                            "global_load_dwordx2 %0, %8, off sc0\n\t"
                            "global_load_dwordx2 %1, %9, off sc0\n\t"
                            "global_load_dwordx2 %2, %10, off sc0\n\t"
                            "global_load_dwordx2 %3, %11, off sc0\n\t"
                            "global_load_dwordx2 %4, %12, off sc0\n\t"
                            "global_load_dwordx2 %5, %13, off sc0\n\t"
                            "global_load_dwordx2 %6, %14, off sc0\n\t"
                            "global_load_dwordx2 %7, %15, off sc0\n\t"
                            "s_waitcnt vmcnt(0)"
                            : "=&v"(p0), "=&v"(p1), "=&v"(p2), "=&v"(p3),
                              "=&v"(p4), "=&v"(p5), "=&v"(p6), "=&v"(p7)
                            : "v"(a0), "v"(a1), "v"(a2), "v"(a3),
                              "v"(a4), "v"(a5), "v"(a6), "v"(a7)
                            : "memory");
                        bool ok = ((int)(p0 >> 32) == phase) & ((int)(p1 >> 32) == phase)
                                & ((int)(p2 >> 32) == phase) & ((int)(p3 >> 32) == phase)
                                & ((int)(p4 >> 32) == phase) & ((int)(p5 >> 32) == phase)
                                & ((int)(p6 >> 32) == phase) & ((int)(p7 >> 32) == phase);
                        if (ok) {   // serial g2=0..7 fold — matches baseline numerics
                            sum = 0.0f;
                            sum += __uint_as_float((unsigned)p0);
                            sum += __uint_as_float((unsigned)p1);
                            sum += __uint_as_float((unsigned)p2);
                            sum += __uint_as_float((unsigned)p3);
                            sum += __uint_as_float((unsigned)p4);
                            sum += __uint_as_float((unsigned)p5);
                            sum += __uint_as_float((unsigned)p6);
                            sum += __uint_as_float((unsigned)p7);
                            have = true;
                        }
                    }
                    if (!have) use_fast = false;
                }
                if (!have) {
                    u64 pk[8];
                    for (;;) {
                        #pragma unroll
                        for (int g2 = 0; g2 < 8; ++g2)
                            pk[g2] = __hip_atomic_load(&zpb[g2 * 128 + tid],
                                                       __ATOMIC_RELAXED, __HIP_MEMORY_SCOPE_AGENT);
                        bool ok = true;
                        #pragma unroll
                        for (int g2 = 0; g2 < 8; ++g2) ok &= ((int)(pk[g2] >> 32) == phase);
                        if (ok) break;
                        __builtin_amdgcn_s_sleep(1);
                    }
                    sum = 0.0f;
                    #pragma unroll
                    for (int g2 = 0; g2 < 8; ++g2) sum += __uint_as_float((unsigned)pk[g2]);
                }
                xs[tid] = xs[tid] + hdt * (sum + b3c);
            }
            __syncthreads();
        }
        // record states at grid index m = t+1 (g==0 writes full rows from xs)
        if (g == 0) {
            const int m = t + 1;
            while (lp < 128 && sidx_sh[lp] == m) {
                if (tid < 128) outb[2 + (size_t)lp * 128 + tid] = xs[tid];
                ++lp;
            }
        }
    }
    // epilogue: scores (g==0; final z in xs)
    if (g == 0 && tid < 128) {
        int lane = tid & 63;
        const int item = (tid < 64) ? pos[batch] : neg[batch];
        const float* ev = emb + (size_t)item * 128;
        float sacc = xs[lane] * ev[lane] + xs[lane + 64] * ev[lane + 64];
        #pragma unroll
        for (int s = 1; s < 64; s <<= 1) sacc += __shfl_xor(sacc, s, 64);
        if (lane == 0) outb[(tid < 64) ? 0 : 1] = sacc;
    }
}

extern "C" void kernel_launch(void* const* d_in, const int* in_sizes, int n_in,
                              void* d_out, int out_size, void* d_ws, size_t ws_size,
                              hipStream_t stream) {
    const float* emb   = (const float*)d_in[0];
    const float* w1    = (const float*)d_in[1];
    const float* b1    = (const float*)d_in[2];
    const float* w2    = (const float*)d_in[3];
    const float* b2    = (const float*)d_in[4];
    const float* usert = (const float*)d_in[5];
    const float* vw1   = (const float*)d_in[6];
    const float* vb1   = (const float*)d_in[7];
    const float* vw2   = (const float*)d_in[8];
    const float* vb2   = (const float*)d_in[9];
    const float* vw3   = (const float*)d_in[10];
    const float* vb3   = (const float*)d_in[11];
    const int*   u     = (const int*)d_in[12];
    const int*   hi    = (const int*)d_in[13];
    const float* ht    = (const float*)d_in[14];
    const int*   hl    = (const int*)d_in[15];
    const int*   pos   = (const int*)d_in[16];
    const int*   neg   = (const int*)d_in[17];
    const float* pt    = (const float*)d_in[18];

    int D = in_sizes[2];         // 128
    int B = in_sizes[12];        // 4
    int L = in_sizes[13] / B;    // 128

    // workspace carve-up: stamped exchange buffers first (8B aligned)
    // fast (L2) copies then slow (memory-side) copies, contiguous for one memset
    u64*   h1f      = (u64*)d_ws;                           // 4*512
    u64*   zpf      = h1f + 4 * 512;                        // 4*1024
    u64*   h1st     = zpf + 4 * 1024;                       // 4*512
    u64*   zpst     = h1st + 4 * 512;                       // 4*1024
    float* jsdv     = (float*)(zpst + 4 * 1024);            // B*L
    float* enc      = jsdv + (size_t)B * L;                 // B*L*D
    float* envsb    = enc + (size_t)B * L * D;              // B*MAX_SEG*D
    float* dt_sched = envsb + (size_t)B * MAX_SEG * D;      // B*MAX_T
    int*   envid    = (int*)(dt_sched + (size_t)B * MAX_T); // B*MAX_T
    int*   stateidx = envid + (size_t)B * MAX_T;            // B*L
    int*   Tcnt     = stateidx + (size_t)B * L;             // B

    hipMemsetAsync(h1f, 0, 2 * (4 * 512 + 4 * 1024) * sizeof(u64), stream); // stamps=0 < phase 1
    encode_kernel<<<B * L, D, 0, stream>>>(emb, hi, w1, b1, w2, b2, enc, (float*)d_out, B, L, D);
    jsd_kernel<<<B * 128, 64, 0, stream>>>(enc, hl, jsdv, L, D);
    plan_kernel<<<B, 64, 0, stream>>>(enc, ht, hl, pt, jsdv, envsb, dt_sched, envid, stateidx, Tcnt, B, L, D);
    ode_coop<<<8 * NWGB, 512, 0, stream>>>(usert, u, vw1, vb1, vw2, vb2, vw3, vb3, emb, pos, neg,
                                           envsb, dt_sched, envid, stateidx, Tcnt,
                                           h1f, zpf, h1st, zpst, (float*)d_out, B);
}